// Round 1
// baseline (567.923 us; speedup 1.0000x reference)
//
#include <hip/hip_runtime.h>

#define N_NODES 100000
#define N_EDGES 1000000
#define IN_CH 166
#define HID 128

// ---------------- graph build ----------------

__global__ __launch_bounds__(256) void k_deg(const int* __restrict__ dst,
                                             int* __restrict__ deg, int e) {
    int i = blockIdx.x * 256 + threadIdx.x;
    if (i < e) atomicAdd(&deg[dst[i]], 1);
}

__global__ __launch_bounds__(256) void k_blocksum(const int* __restrict__ deg,
                                                  int* __restrict__ partial, int n) {
    __shared__ int s[256];
    int t = threadIdx.x;
    int base = blockIdx.x * 1024;
    int sum = 0;
#pragma unroll
    for (int j = 0; j < 4; ++j) {
        int g = base + t + j * 256;
        if (g < n) sum += deg[g];
    }
    s[t] = sum;
    __syncthreads();
    for (int stp = 128; stp > 0; stp >>= 1) {
        if (t < stp) s[t] += s[t + stp];
        __syncthreads();
    }
    if (t == 0) partial[blockIdx.x] = s[0];
}

__global__ void k_scanpartial(int* partial, int nb) {
    if (threadIdx.x == 0 && blockIdx.x == 0) {
        int run = 0;
        for (int i = 0; i < nb; ++i) { int v = partial[i]; partial[i] = run; run += v; }
    }
}

__global__ __launch_bounds__(256) void k_scanfinal(const int* __restrict__ deg,
                                                   const int* __restrict__ partial,
                                                   int* __restrict__ offsets, int n) {
    __shared__ int s[256];
    int t = threadIdx.x;
    int base = blockIdx.x * 1024;
    int v[4];
    int loc = 0;
#pragma unroll
    for (int j = 0; j < 4; ++j) {
        int g = base + t * 4 + j;
        v[j] = (g < n) ? deg[g] : 0;
        loc += v[j];
    }
    s[t] = loc;
    __syncthreads();
    int val = loc;
    for (int stp = 1; stp < 256; stp <<= 1) {
        int other = (t >= stp) ? s[t - stp] : 0;
        __syncthreads();
        val += other;
        s[t] = val;
        __syncthreads();
    }
    int run = val - loc + partial[blockIdx.x];
#pragma unroll
    for (int j = 0; j < 4; ++j) {
        int g = base + t * 4 + j;
        if (g < n) {
            offsets[g] = run;
            run += v[j];
            if (g == n - 1) offsets[n] = run;
        }
    }
}

__global__ __launch_bounds__(256) void k_fill(const int* __restrict__ src,
                                              const int* __restrict__ dst,
                                              int* __restrict__ cursor,
                                              int* __restrict__ ssrc, int e) {
    int i = blockIdx.x * 256 + threadIdx.x;
    if (i < e) {
        int p = atomicAdd(&cursor[dst[i]], 1);
        ssrc[p] = src[i];
    }
}

// ---------------- projection: y = in @ Wl ; r = in @ Wr + b ----------------
// block = 256 threads: out = tid&127, node-half = tid>>7; 16 nodes per block.
// in_s transposed with padded stride 20 floats (16B-aligned float4 reads,
// broadcast reads per wave, 8-way-conflict writes on tiny staging volume).

template <int K>
__global__ __launch_bounds__(256) void k_proj(const float* __restrict__ in,
                                              const float* __restrict__ Wl,
                                              const float* __restrict__ Wr,
                                              const float* __restrict__ bias,
                                              float* __restrict__ y,
                                              float* __restrict__ r) {
    __shared__ float in_s[K * 20];
    const int tid = threadIdx.x;
    const int out = tid & 127;
    const int mh = tid >> 7;  // 0 or 1
    const int n0 = blockIdx.x * 16;

    for (int idx = tid; idx < 16 * K; idx += 256) {
        int m = idx / K;
        int k = idx - m * K;
        in_s[k * 20 + m] = in[(size_t)(n0 + m) * K + k];
    }
    __syncthreads();

    float accl[8] = {0.f, 0.f, 0.f, 0.f, 0.f, 0.f, 0.f, 0.f};
    float accr[8] = {0.f, 0.f, 0.f, 0.f, 0.f, 0.f, 0.f, 0.f};

#pragma unroll 2
    for (int k = 0; k < K; ++k) {
        float wl = Wl[k * 128 + out];
        float wr = Wr[k * 128 + out];
        const float4 a0 = *(const float4*)&in_s[k * 20 + mh * 8];
        const float4 a1 = *(const float4*)&in_s[k * 20 + mh * 8 + 4];
        accl[0] += a0.x * wl; accr[0] += a0.x * wr;
        accl[1] += a0.y * wl; accr[1] += a0.y * wr;
        accl[2] += a0.z * wl; accr[2] += a0.z * wr;
        accl[3] += a0.w * wl; accr[3] += a0.w * wr;
        accl[4] += a1.x * wl; accr[4] += a1.x * wr;
        accl[5] += a1.y * wl; accr[5] += a1.y * wr;
        accl[6] += a1.z * wl; accr[6] += a1.z * wr;
        accl[7] += a1.w * wl; accr[7] += a1.w * wr;
    }

    float bv = bias[out];
#pragma unroll
    for (int j = 0; j < 8; ++j) {
        size_t node = (size_t)(n0 + mh * 8 + j);
        y[node * 128 + out] = accl[j];
        r[node * 128 + out] = accr[j] + bv;
    }
}

// ---------------- aggregation: hr = relu?(gathered_mean(y) + hr) ----------------
// one wave per node; 64 lanes x float2 = 128 channels. In-place on hr.

__global__ __launch_bounds__(256) void k_agg(const float* __restrict__ y,
                                             const int* __restrict__ offsets,
                                             const int* __restrict__ ssrc,
                                             float* hr, int do_relu) {
    const int lane = threadIdx.x & 63;
    const int node = blockIdx.x * 4 + (threadIdx.x >> 6);
    const int off0 = offsets[node];
    const int off1 = offsets[node + 1];
    const int deg = off1 - off0;

    float accx = 0.f, accy = 0.f;
    for (int cbase = 0; cbase < deg; cbase += 64) {
        int cnt = min(64, deg - cbase);
        int idxv = ((cbase + lane) < deg) ? ssrc[off0 + cbase + lane] : 0;
        int e = 0;
        for (; e + 1 < cnt; e += 2) {
            int s0 = __shfl(idxv, e);
            int s1 = __shfl(idxv, e + 1);
            float2 v0 = *(const float2*)&y[(size_t)s0 * 128 + lane * 2];
            float2 v1 = *(const float2*)&y[(size_t)s1 * 128 + lane * 2];
            accx += v0.x + v1.x;
            accy += v0.y + v1.y;
        }
        if (e < cnt) {
            int s0 = __shfl(idxv, e);
            float2 v0 = *(const float2*)&y[(size_t)s0 * 128 + lane * 2];
            accx += v0.x;
            accy += v0.y;
        }
    }

    float inv = 1.0f / (float)(deg > 0 ? deg : 1);
    size_t base = (size_t)node * 128 + lane * 2;
    float2 rv = *(const float2*)&hr[base];
    float o0 = accx * inv + rv.x;
    float o1 = accy * inv + rv.y;
    if (do_relu) {
        o0 = fmaxf(o0, 0.f);
        o1 = fmaxf(o1, 0.f);
    }
    float2 res;
    res.x = o0;
    res.y = o1;
    *(float2*)&hr[base] = res;
}

// ---------------- layer 2 projection (HID -> 2) ----------------
// one wave per node; each lane covers k = 2*lane, 2*lane+1; wave-reduce.

__global__ __launch_bounds__(256) void k_proj2(const float* __restrict__ h,
                                               const float* __restrict__ Wl,
                                               const float* __restrict__ Wr,
                                               const float* __restrict__ bias,
                                               float* __restrict__ z,
                                               float* __restrict__ r2) {
    const int lane = threadIdx.x & 63;
    const int node = blockIdx.x * 4 + (threadIdx.x >> 6);
    float2 hv = *(const float2*)&h[(size_t)node * 128 + lane * 2];
    float4 wl = *(const float4*)&Wl[lane * 4];
    float4 wr = *(const float4*)&Wr[lane * 4];
    float zl0 = hv.x * wl.x + hv.y * wl.z;
    float zl1 = hv.x * wl.y + hv.y * wl.w;
    float zr0 = hv.x * wr.x + hv.y * wr.z;
    float zr1 = hv.x * wr.y + hv.y * wr.w;
    for (int d = 32; d; d >>= 1) {
        zl0 += __shfl_xor(zl0, d);
        zl1 += __shfl_xor(zl1, d);
        zr0 += __shfl_xor(zr0, d);
        zr1 += __shfl_xor(zr1, d);
    }
    if (lane == 0) {
        z[node * 2 + 0] = zl0;
        z[node * 2 + 1] = zl1;
        r2[node * 2 + 0] = zr0 + bias[0];
        r2[node * 2 + 1] = zr1 + bias[1];
    }
}

// ---------------- layer 2 aggregation (2 channels) ----------------

__global__ __launch_bounds__(256) void k_agg2(const float* __restrict__ z,
                                              const float* __restrict__ r2,
                                              const int* __restrict__ offsets,
                                              const int* __restrict__ ssrc,
                                              float* __restrict__ out) {
    int n = blockIdx.x * 256 + threadIdx.x;
    if (n >= N_NODES) return;
    int off0 = offsets[n];
    int off1 = offsets[n + 1];
    float a0 = 0.f, a1 = 0.f;
    for (int e = off0; e < off1; ++e) {
        int s = ssrc[e];
        a0 += z[s * 2];
        a1 += z[s * 2 + 1];
    }
    float inv = 1.0f / (float)max(off1 - off0, 1);
    out[n * 2 + 0] = a0 * inv + r2[n * 2 + 0];
    out[n * 2 + 1] = a1 * inv + r2[n * 2 + 1];
}

// ---------------- launcher ----------------

extern "C" void kernel_launch(void* const* d_in, const int* in_sizes, int n_in,
                              void* d_out, int out_size, void* d_ws, size_t ws_size,
                              hipStream_t stream) {
    const float* x   = (const float*)d_in[0];
    const int*   ei  = (const int*)d_in[1];   // [2, E] int32
    const float* Wl0 = (const float*)d_in[2];
    const float* bl0 = (const float*)d_in[3];
    const float* Wr0 = (const float*)d_in[4];
    const float* Wl1 = (const float*)d_in[5];
    const float* bl1 = (const float*)d_in[6];
    const float* Wr1 = (const float*)d_in[7];
    const float* Wl2 = (const float*)d_in[8];
    const float* bl2 = (const float*)d_in[9];
    const float* Wr2 = (const float*)d_in[10];
    float* out = (float*)d_out;

    const int* srcp = ei;
    const int* dstp = ei + N_EDGES;

    char* ws = (char*)d_ws;
    size_t off = 0;
    auto alloc = [&](size_t bytes) -> void* {
        void* p = ws + off;
        off += (bytes + 255) & ~(size_t)255;
        return p;
    };
    int* deg     = (int*)alloc((size_t)N_NODES * 4);
    int* offsets = (int*)alloc((size_t)(N_NODES + 1) * 4);
    int* cursor  = (int*)alloc((size_t)N_NODES * 4);
    int* partial = (int*)alloc(128 * 4);
    int* ssrc    = (int*)alloc((size_t)N_EDGES * 4);
    float* ybuf  = (float*)alloc((size_t)N_NODES * HID * 4);
    float* rA    = (float*)alloc((size_t)N_NODES * HID * 4);
    float* rB    = (float*)alloc((size_t)N_NODES * HID * 4);
    (void)ws_size; (void)n_in; (void)in_sizes; (void)out_size;

    // ---- graph build (CSR by dst) ----
    hipMemsetAsync(deg, 0, (size_t)N_NODES * 4, stream);
    k_deg<<<(N_EDGES + 255) / 256, 256, 0, stream>>>(dstp, deg, N_EDGES);
    int nb = (N_NODES + 1023) / 1024;  // 98
    k_blocksum<<<nb, 256, 0, stream>>>(deg, partial, N_NODES);
    k_scanpartial<<<1, 64, 0, stream>>>(partial, nb);
    k_scanfinal<<<nb, 256, 0, stream>>>(deg, partial, offsets, N_NODES);
    hipMemcpyAsync(cursor, offsets, (size_t)N_NODES * 4, hipMemcpyDeviceToDevice, stream);
    k_fill<<<(N_EDGES + 255) / 256, 256, 0, stream>>>(srcp, dstp, cursor, ssrc, N_EDGES);

    // ---- layer 0: x(166) -> h0(128) in rA ----
    k_proj<IN_CH><<<N_NODES / 16, 256, 0, stream>>>(x, Wl0, Wr0, bl0, ybuf, rA);
    k_agg<<<N_NODES / 4, 256, 0, stream>>>(ybuf, offsets, ssrc, rA, 1);

    // ---- layer 1: h0(128) -> h1(128) in rB ----
    k_proj<HID><<<N_NODES / 16, 256, 0, stream>>>(rA, Wl1, Wr1, bl1, ybuf, rB);
    k_agg<<<N_NODES / 4, 256, 0, stream>>>(ybuf, offsets, ssrc, rB, 1);

    // ---- layer 2: h1(128) -> out(2) ----
    float* z  = ybuf;  // [N,2] reuse
    float* r2 = rA;    // [N,2] reuse
    k_proj2<<<N_NODES / 4, 256, 0, stream>>>(rB, Wl2, Wr2, bl2, z, r2);
    k_agg2<<<(N_NODES + 255) / 256, 256, 0, stream>>>(z, r2, offsets, ssrc, out);
}

// Round 2
// 362.176 us; speedup vs baseline: 1.5681x; 1.5681x over previous
//
#include <hip/hip_runtime.h>

#define N_NODES 100000
#define N_EDGES 1000000
#define IN_CH 166
#define HID 128
#define M_PAD 100032   // 1563 * 64

typedef unsigned short u16;
typedef __attribute__((ext_vector_type(8))) short short8;
typedef __attribute__((ext_vector_type(4))) float f32x4;

static __device__ __forceinline__ u16 f2bf(float f) {
    unsigned u = __float_as_uint(f);
    u += 0x7FFF + ((u >> 16) & 1);   // RNE
    return (u16)(u >> 16);
}
static __device__ __forceinline__ unsigned pk2(float a, float b) {
    return (unsigned)f2bf(a) | ((unsigned)f2bf(b) << 16);
}

// ---------------- graph build ----------------

__global__ __launch_bounds__(256) void k_deg(const int* __restrict__ dst,
                                             int* __restrict__ deg, int e) {
    int i = blockIdx.x * 256 + threadIdx.x;
    if (i < e) atomicAdd(&deg[dst[i]], 1);
}

__global__ __launch_bounds__(256) void k_blocksum(const int* __restrict__ deg,
                                                  int* __restrict__ partial, int n) {
    __shared__ int s[256];
    int t = threadIdx.x;
    int base = blockIdx.x * 1024;
    int sum = 0;
#pragma unroll
    for (int j = 0; j < 4; ++j) {
        int g = base + t + j * 256;
        if (g < n) sum += deg[g];
    }
    s[t] = sum;
    __syncthreads();
    for (int stp = 128; stp > 0; stp >>= 1) {
        if (t < stp) s[t] += s[t + stp];
        __syncthreads();
    }
    if (t == 0) partial[blockIdx.x] = s[0];
}

__global__ void k_scanpartial(int* partial, int nb) {
    if (threadIdx.x == 0 && blockIdx.x == 0) {
        int run = 0;
        for (int i = 0; i < nb; ++i) { int v = partial[i]; partial[i] = run; run += v; }
    }
}

__global__ __launch_bounds__(256) void k_scanfinal(const int* __restrict__ deg,
                                                   const int* __restrict__ partial,
                                                   int* __restrict__ offsets, int n) {
    __shared__ int s[256];
    int t = threadIdx.x;
    int base = blockIdx.x * 1024;
    int v[4];
    int loc = 0;
#pragma unroll
    for (int j = 0; j < 4; ++j) {
        int g = base + t * 4 + j;
        v[j] = (g < n) ? deg[g] : 0;
        loc += v[j];
    }
    s[t] = loc;
    __syncthreads();
    int val = loc;
    for (int stp = 1; stp < 256; stp <<= 1) {
        int other = (t >= stp) ? s[t - stp] : 0;
        __syncthreads();
        val += other;
        s[t] = val;
        __syncthreads();
    }
    int run = val - loc + partial[blockIdx.x];
#pragma unroll
    for (int j = 0; j < 4; ++j) {
        int g = base + t * 4 + j;
        if (g < n) {
            offsets[g] = run;
            run += v[j];
            if (g == n - 1) offsets[n] = run;
        }
    }
}

__global__ __launch_bounds__(256) void k_fill(const int* __restrict__ src,
                                              const int* __restrict__ dst,
                                              int* __restrict__ cursor,
                                              int* __restrict__ ssrc, int e) {
    int i = blockIdx.x * 256 + threadIdx.x;
    if (i < e) {
        int p = atomicAdd(&cursor[dst[i]], 1);
        ssrc[p] = src[i];
    }
}

// ---------------- x fp32 -> bf16, padded [M_PAD x 192] ----------------

__global__ __launch_bounds__(256) void k_cvt(const float* __restrict__ x,
                                             u16* __restrict__ xb) {
    int idx = blockIdx.x * 256 + threadIdx.x;          // M_PAD*24 threads
    int row = idx / 24;
    int c = idx - row * 24;
    int k0 = c * 8;
    float v[8];
#pragma unroll
    for (int j = 0; j < 8; ++j) {
        int k = k0 + j;
        v[j] = (row < N_NODES && k < IN_CH) ? x[(size_t)row * IN_CH + k] : 0.f;
    }
    int4 o;
    o.x = pk2(v[0], v[1]);
    o.y = pk2(v[2], v[3]);
    o.z = pk2(v[4], v[5]);
    o.w = pk2(v[6], v[7]);
    *(int4*)(xb + (size_t)row * 192 + k0) = o;
}

// ---------------- weight prep: Wl|Wr -> bf16 MFMA fragments ----------------
// frag[((kt*16 + ct)*64 + lane)*8 + j] = Wcat[kt*32 + (lane>>4)*8 + j][ct*16 + (lane&15)]

__global__ __launch_bounds__(64) void k_wprep(const float* __restrict__ Wl,
                                              const float* __restrict__ Wr,
                                              int Kact, u16* __restrict__ wf) {
    int lane = threadIdx.x;
    int kt = blockIdx.x >> 4;
    int ct = blockIdx.x & 15;
    int col = ct * 16 + (lane & 15);
    const float* W = (col < 128) ? Wl : Wr;
    int wcol = col & 127;
    float v[8];
#pragma unroll
    for (int j = 0; j < 8; ++j) {
        int row = kt * 32 + (lane >> 4) * 8 + j;
        v[j] = (row < Kact) ? W[(size_t)row * 128 + wcol] : 0.f;
    }
    int4 o;
    o.x = pk2(v[0], v[1]);
    o.y = pk2(v[2], v[3]);
    o.z = pk2(v[4], v[5]);
    o.w = pk2(v[6], v[7]);
    *(int4*)(wf + ((size_t)blockIdx.x * 64 + lane) * 8) = o;
}

// ---------------- MFMA projection: [64 x KP] @ [KP x 256] per block --------
// cols 0..127 -> y (bf16), cols 128..255 -> r (fp32, +bias)

template <int KP>
__global__ __launch_bounds__(256) void k_projmm(const u16* __restrict__ in,
                                                const u16* __restrict__ wf,
                                                const float* __restrict__ bias,
                                                u16* __restrict__ y,
                                                float* __restrict__ r) {
    constexpr int STR = KP + 8;                 // LDS row stride (bf16 elems)
    constexpr int CH = KP / 8;                  // 16B chunks per row
    __shared__ u16 sA[64 * STR];

    const int tid = threadIdx.x;
    const int n0 = blockIdx.x * 64;

    for (int c = tid; c < 64 * CH; c += 256) {
        int row = c / CH;
        int cc = c - row * CH;
        int4 v = *(const int4*)(in + (size_t)(n0 + row) * KP + cc * 8);
        *(int4*)(&sA[row * STR + cc * 8]) = v;
    }
    __syncthreads();

    const int wv = tid >> 6;
    const int lane = tid & 63;
    const int r16 = lane & 15;
    const int kq = lane >> 4;   // 0..3

    f32x4 acc[4][4];
#pragma unroll
    for (int a = 0; a < 4; ++a)
#pragma unroll
        for (int b = 0; b < 4; ++b) acc[a][b] = (f32x4){0.f, 0.f, 0.f, 0.f};

#pragma unroll
    for (int kt = 0; kt < KP / 32; ++kt) {
        short8 af[4], bf[4];
#pragma unroll
        for (int rt = 0; rt < 4; ++rt)
            af[rt] = *(const short8*)(&sA[(rt * 16 + r16) * STR + kt * 32 + kq * 8]);
#pragma unroll
        for (int c = 0; c < 4; ++c)
            bf[c] = *(const short8*)(wf + (((size_t)(kt * 16 + wv * 4 + c) * 64 + lane) * 8));
#pragma unroll
        for (int rt = 0; rt < 4; ++rt)
#pragma unroll
            for (int c = 0; c < 4; ++c)
                acc[rt][c] = __builtin_amdgcn_mfma_f32_16x16x32_bf16(af[rt], bf[c], acc[rt][c], 0, 0, 0);
    }

    if (wv < 2) {
        // y half, bf16
#pragma unroll
        for (int rt = 0; rt < 4; ++rt)
#pragma unroll
            for (int c = 0; c < 4; ++c) {
                int col = wv * 64 + c * 16 + r16;
#pragma unroll
                for (int i = 0; i < 4; ++i) {
                    int row = n0 + rt * 16 + kq * 4 + i;
                    y[(size_t)row * 128 + col] = f2bf(acc[rt][c][i]);
                }
            }
    } else {
        // r half, fp32 + bias
        float bv[4];
#pragma unroll
        for (int c = 0; c < 4; ++c) bv[c] = bias[(wv - 2) * 64 + c * 16 + r16];
#pragma unroll
        for (int rt = 0; rt < 4; ++rt)
#pragma unroll
            for (int c = 0; c < 4; ++c) {
                int col = (wv - 2) * 64 + c * 16 + r16;
#pragma unroll
                for (int i = 0; i < 4; ++i) {
                    int row = n0 + rt * 16 + kq * 4 + i;
                    r[(size_t)row * 128 + col] = acc[rt][c][i] + bv[c];
                }
            }
    }
}

// ---------------- aggregation: h = relu(mean_gather(yb) + r), bf16 out -----
// one wave per node; 4 edges per step; 16 lanes x 16B per edge row.

__global__ __launch_bounds__(256) void k_aggb(const u16* __restrict__ yb,
                                              const float* __restrict__ r,
                                              const int* __restrict__ offsets,
                                              const int* __restrict__ ssrc,
                                              u16* __restrict__ h) {
    const int lane = threadIdx.x & 63;
    const int node = blockIdx.x * 4 + (threadIdx.x >> 6);
    const int g = lane >> 4;     // edge subgroup 0..3
    const int i = lane & 15;     // channel chunk (8 ch)
    const int off0 = offsets[node];
    const int deg = offsets[node + 1] - off0;

    float acc[8] = {0.f, 0.f, 0.f, 0.f, 0.f, 0.f, 0.f, 0.f};

    for (int cb = 0; cb < deg; cb += 64) {
        int idxv = (cb + lane < deg) ? ssrc[off0 + cb + lane] : 0;
        int steps = min(16, (deg - cb + 3) >> 2);
        for (int s = 0; s < steps; ++s) {
            int e = cb + s * 4 + g;
            int srci = __shfl(idxv, s * 4 + g);
            if (e < deg) {
                int4 v = *(const int4*)(yb + (size_t)srci * 128 + i * 8);
                const unsigned* w = (const unsigned*)&v;
#pragma unroll
                for (int q = 0; q < 4; ++q) {
                    acc[q * 2]     += __uint_as_float(w[q] << 16);
                    acc[q * 2 + 1] += __uint_as_float(w[q] & 0xFFFF0000u);
                }
            }
        }
    }
#pragma unroll
    for (int q = 0; q < 8; ++q) {
        acc[q] += __shfl_xor(acc[q], 16);
        acc[q] += __shfl_xor(acc[q], 32);
    }
    if (g == 0) {
        float inv = 1.f / (float)max(deg, 1);
        const float4* rp = (const float4*)(r + (size_t)node * 128 + i * 8);
        float4 r0 = rp[0], r1 = rp[1];
        float o[8];
        o[0] = fmaxf(acc[0] * inv + r0.x, 0.f);
        o[1] = fmaxf(acc[1] * inv + r0.y, 0.f);
        o[2] = fmaxf(acc[2] * inv + r0.z, 0.f);
        o[3] = fmaxf(acc[3] * inv + r0.w, 0.f);
        o[4] = fmaxf(acc[4] * inv + r1.x, 0.f);
        o[5] = fmaxf(acc[5] * inv + r1.y, 0.f);
        o[6] = fmaxf(acc[6] * inv + r1.z, 0.f);
        o[7] = fmaxf(acc[7] * inv + r1.w, 0.f);
        int4 ov;
        ov.x = pk2(o[0], o[1]);
        ov.y = pk2(o[2], o[3]);
        ov.z = pk2(o[4], o[5]);
        ov.w = pk2(o[6], o[7]);
        *(int4*)(h + (size_t)node * 128 + i * 8) = ov;
    }
}

// ---------------- layer 2 projection (bf16 h -> 2ch) ----------------

__global__ __launch_bounds__(256) void k_proj2b(const u16* __restrict__ h,
                                                const float* __restrict__ Wl,
                                                const float* __restrict__ Wr,
                                                const float* __restrict__ bias,
                                                float* __restrict__ z,
                                                float* __restrict__ r2) {
    const int lane = threadIdx.x & 63;
    const int node = blockIdx.x * 4 + (threadIdx.x >> 6);
    unsigned hv = *(const unsigned*)(h + (size_t)node * 128 + lane * 2);
    float h0 = __uint_as_float(hv << 16);
    float h1 = __uint_as_float(hv & 0xFFFF0000u);
    float4 wl = *(const float4*)&Wl[lane * 4];
    float4 wr = *(const float4*)&Wr[lane * 4];
    float zl0 = h0 * wl.x + h1 * wl.z;
    float zl1 = h0 * wl.y + h1 * wl.w;
    float zr0 = h0 * wr.x + h1 * wr.z;
    float zr1 = h0 * wr.y + h1 * wr.w;
    for (int d = 32; d; d >>= 1) {
        zl0 += __shfl_xor(zl0, d);
        zl1 += __shfl_xor(zl1, d);
        zr0 += __shfl_xor(zr0, d);
        zr1 += __shfl_xor(zr1, d);
    }
    if (lane == 0) {
        z[node * 2 + 0] = zl0;
        z[node * 2 + 1] = zl1;
        r2[node * 2 + 0] = zr0 + bias[0];
        r2[node * 2 + 1] = zr1 + bias[1];
    }
}

// ---------------- layer 2 aggregation (2 channels) ----------------

__global__ __launch_bounds__(256) void k_agg2(const float* __restrict__ z,
                                              const float* __restrict__ r2,
                                              const int* __restrict__ offsets,
                                              const int* __restrict__ ssrc,
                                              float* __restrict__ out) {
    int n = blockIdx.x * 256 + threadIdx.x;
    if (n >= N_NODES) return;
    int off0 = offsets[n];
    int off1 = offsets[n + 1];
    float a0 = 0.f, a1 = 0.f;
    for (int e = off0; e < off1; ++e) {
        int s = ssrc[e];
        a0 += z[s * 2];
        a1 += z[s * 2 + 1];
    }
    float inv = 1.0f / (float)max(off1 - off0, 1);
    out[n * 2 + 0] = a0 * inv + r2[n * 2 + 0];
    out[n * 2 + 1] = a1 * inv + r2[n * 2 + 1];
}

// ---------------- launcher ----------------

extern "C" void kernel_launch(void* const* d_in, const int* in_sizes, int n_in,
                              void* d_out, int out_size, void* d_ws, size_t ws_size,
                              hipStream_t stream) {
    const float* x   = (const float*)d_in[0];
    const int*   ei  = (const int*)d_in[1];
    const float* Wl0 = (const float*)d_in[2];
    const float* bl0 = (const float*)d_in[3];
    const float* Wr0 = (const float*)d_in[4];
    const float* Wl1 = (const float*)d_in[5];
    const float* bl1 = (const float*)d_in[6];
    const float* Wr1 = (const float*)d_in[7];
    const float* Wl2 = (const float*)d_in[8];
    const float* bl2 = (const float*)d_in[9];
    const float* Wr2 = (const float*)d_in[10];
    float* out = (float*)d_out;

    const int* srcp = ei;
    const int* dstp = ei + N_EDGES;

    char* ws = (char*)d_ws;
    size_t off = 0;
    auto alloc = [&](size_t bytes) -> void* {
        void* p = ws + off;
        off += (bytes + 255) & ~(size_t)255;
        return p;
    };
    int* deg     = (int*)alloc((size_t)N_NODES * 4);
    int* offsets = (int*)alloc((size_t)(N_NODES + 1) * 4);
    int* cursor  = (int*)alloc((size_t)N_NODES * 4);
    int* partial = (int*)alloc(128 * 4);
    int* ssrc    = (int*)alloc((size_t)N_EDGES * 4);
    u16* xb      = (u16*)alloc((size_t)M_PAD * 192 * 2);   // also reused as h0
    u16* wf0     = (u16*)alloc((size_t)192 * 256 * 2);
    u16* wf1     = (u16*)alloc((size_t)128 * 256 * 2);
    u16* ybuf    = (u16*)alloc((size_t)M_PAD * 128 * 2);   // also reused as z/r2
    float* rbuf  = (float*)alloc((size_t)M_PAD * 128 * 4);
    u16* h1      = (u16*)alloc((size_t)M_PAD * 128 * 2);
    (void)ws_size; (void)n_in; (void)in_sizes; (void)out_size;

    u16* h0 = xb;  // reuse: xb dead after proj0
    float* z  = (float*)ybuf;                      // [N,2]
    float* r2 = (float*)((char*)ybuf + 1048576);   // [N,2]

    // ---- graph build (CSR by dst) ----
    hipMemsetAsync(deg, 0, (size_t)N_NODES * 4, stream);
    k_deg<<<(N_EDGES + 255) / 256, 256, 0, stream>>>(dstp, deg, N_EDGES);
    int nb = (N_NODES + 1023) / 1024;
    k_blocksum<<<nb, 256, 0, stream>>>(deg, partial, N_NODES);
    k_scanpartial<<<1, 64, 0, stream>>>(partial, nb);
    k_scanfinal<<<nb, 256, 0, stream>>>(deg, partial, offsets, N_NODES);
    hipMemcpyAsync(cursor, offsets, (size_t)N_NODES * 4, hipMemcpyDeviceToDevice, stream);
    k_fill<<<(N_EDGES + 255) / 256, 256, 0, stream>>>(srcp, dstp, cursor, ssrc, N_EDGES);

    // ---- input/weight conversion ----
    k_cvt<<<(M_PAD * 24) / 256, 256, 0, stream>>>(x, xb);
    k_wprep<<<(192 / 32) * 16, 64, 0, stream>>>(Wl0, Wr0, IN_CH, wf0);
    k_wprep<<<(128 / 32) * 16, 64, 0, stream>>>(Wl1, Wr1, HID, wf1);

    // ---- layer 0 ----
    k_projmm<192><<<M_PAD / 64, 256, 0, stream>>>(xb, wf0, bl0, ybuf, rbuf);
    k_aggb<<<N_NODES / 4, 256, 0, stream>>>(ybuf, rbuf, offsets, ssrc, h0);

    // ---- layer 1 ----
    k_projmm<128><<<M_PAD / 64, 256, 0, stream>>>(h0, wf1, bl1, ybuf, rbuf);
    k_aggb<<<N_NODES / 4, 256, 0, stream>>>(ybuf, rbuf, offsets, ssrc, h1);

    // ---- layer 2 ----
    k_proj2b<<<N_NODES / 4, 256, 0, stream>>>(h1, Wl2, Wr2, bl2, z, r2);
    k_agg2<<<(N_NODES + 255) / 256, 256, 0, stream>>>(z, r2, offsets, ssrc, out);
}

// Round 3
// 263.611 us; speedup vs baseline: 2.1544x; 1.3739x over previous
//
#include <hip/hip_runtime.h>

#define N_NODES 100000
#define N_EDGES 1000000
#define IN_CH 166
#define HID 128
#define M_PAD 100032   // 1563 * 64
#define BSHIFT 9
#define NBUCK 196      // ceil(100000 / 512)

typedef unsigned short u16;
typedef __attribute__((ext_vector_type(8))) short short8;
typedef __attribute__((ext_vector_type(4))) float f32x4;

static __device__ __forceinline__ u16 f2bf(float f) {
    unsigned u = __float_as_uint(f);
    u += 0x7FFF + ((u >> 16) & 1);   // RNE
    return (u16)(u >> 16);
}
static __device__ __forceinline__ unsigned pk2(float a, float b) {
    return (unsigned)f2bf(a) | ((unsigned)f2bf(b) << 16);
}

// ================= graph build: two-level counting sort =================
// bucket = dst >> 9 (512 nodes / bucket, 196 buckets)

// ---- pass 1: bucket histogram (per-block LDS, then 196 global atomics) ----
__global__ __launch_bounds__(256) void k_bincount(const int* __restrict__ dst,
                                                  int* __restrict__ bcnt) {
    __shared__ int cnt[NBUCK];
    const int t = threadIdx.x;
    if (t < NBUCK) cnt[t] = 0;
    __syncthreads();
#pragma unroll
    for (int j = 0; j < 4; ++j) {
        int e4 = blockIdx.x * 1024 + j * 256 + t;   // int4 index
        if (e4 < N_EDGES / 4) {
            int4 d = ((const int4*)dst)[e4];
            atomicAdd(&cnt[d.x >> BSHIFT], 1);
            atomicAdd(&cnt[d.y >> BSHIFT], 1);
            atomicAdd(&cnt[d.z >> BSHIFT], 1);
            atomicAdd(&cnt[d.w >> BSHIFT], 1);
        }
    }
    __syncthreads();
    if (t < NBUCK && cnt[t] > 0) atomicAdd(&bcnt[t], cnt[t]);
}

// ---- pass 2: scan bucket counts -> bucket_base, gcursor ----
__global__ __launch_bounds__(256) void k_bucketscan(const int* __restrict__ bcnt,
                                                    int* __restrict__ bucket_base,
                                                    int* __restrict__ gcursor,
                                                    int* __restrict__ offsets) {
    __shared__ int ws[256];
    const int t = threadIdx.x;
    int loc = (t < NBUCK) ? bcnt[t] : 0;
    ws[t] = loc;
    __syncthreads();
    int val = loc;
    for (int stp = 1; stp < 256; stp <<= 1) {
        int other = (t >= stp) ? ws[t - stp] : 0;
        __syncthreads();
        val += other;
        ws[t] = val;
        __syncthreads();
    }
    int excl = val - loc;
    if (t < NBUCK) {
        bucket_base[t] = excl;
        gcursor[t] = excl;
    }
    if (t == 255) bucket_base[NBUCK] = val;     // = N_EDGES
    if (t == 0) offsets[N_NODES] = N_EDGES;
}

// ---- pass 3: scatter (src,dst) pairs into bucket-contiguous staging ----
__global__ __launch_bounds__(256) void k_scatter(const int* __restrict__ src,
                                                 const int* __restrict__ dst,
                                                 int* __restrict__ gcursor,
                                                 int2* __restrict__ stage) {
    __shared__ int cnt[NBUCK];
    __shared__ int base[NBUCK];
    const int t = threadIdx.x;
    if (t < NBUCK) cnt[t] = 0;
    __syncthreads();

    int4 s4[4], d4[4];
    bool ok[4];
#pragma unroll
    for (int j = 0; j < 4; ++j) {
        int e4 = blockIdx.x * 1024 + j * 256 + t;
        ok[j] = (e4 < N_EDGES / 4);
        if (ok[j]) {
            s4[j] = ((const int4*)src)[e4];
            d4[j] = ((const int4*)dst)[e4];
            atomicAdd(&cnt[d4[j].x >> BSHIFT], 1);
            atomicAdd(&cnt[d4[j].y >> BSHIFT], 1);
            atomicAdd(&cnt[d4[j].z >> BSHIFT], 1);
            atomicAdd(&cnt[d4[j].w >> BSHIFT], 1);
        }
    }
    __syncthreads();
    if (t < NBUCK && cnt[t] > 0) base[t] = atomicAdd(&gcursor[t], cnt[t]);
    __syncthreads();

#pragma unroll
    for (int j = 0; j < 4; ++j) {
        if (ok[j]) {
            const int ss[4] = {s4[j].x, s4[j].y, s4[j].z, s4[j].w};
            const int dd[4] = {d4[j].x, d4[j].y, d4[j].z, d4[j].w};
#pragma unroll
            for (int q = 0; q < 4; ++q) {
                int b = dd[q] >> BSHIFT;
                int r = atomicSub(&cnt[b], 1) - 1;
                int2 pr;
                pr.x = ss[q];
                pr.y = dd[q];
                stage[base[b] + r] = pr;
            }
        }
    }
}

// ---- pass 4: per-bucket fine CSR (LDS count + scan + scatter) ----
__global__ __launch_bounds__(256) void k_csr(const int2* __restrict__ stage,
                                             const int* __restrict__ bucket_base,
                                             int* __restrict__ offsets,
                                             int* __restrict__ ssrc) {
    __shared__ int cnt[512];
    __shared__ int ws[256];
    const int t = threadIdx.x;
    const int b = blockIdx.x;
    const int nb0 = b << BSHIFT;
    const int nn = min(512, N_NODES - nb0);
    const int e0 = bucket_base[b];
    const int m = bucket_base[b + 1] - e0;

    cnt[t] = 0;
    cnt[t + 256] = 0;
    __syncthreads();

    for (int i = t; i < m; i += 256) {
        int d = stage[e0 + i].y;
        atomicAdd(&cnt[d - nb0], 1);
    }
    __syncthreads();

    // 512-entry exclusive scan: each thread owns 2 consecutive entries
    int c0 = cnt[2 * t];
    int c1 = cnt[2 * t + 1];
    int loc = c0 + c1;
    ws[t] = loc;
    __syncthreads();
    int val = loc;
    for (int stp = 1; stp < 256; stp <<= 1) {
        int other = (t >= stp) ? ws[t - stp] : 0;
        __syncthreads();
        val += other;
        ws[t] = val;
        __syncthreads();
    }
    int p0 = e0 + (val - loc);
    int p1 = p0 + c0;
    if (2 * t < nn) offsets[nb0 + 2 * t] = p0;
    if (2 * t + 1 < nn) offsets[nb0 + 2 * t + 1] = p1;
    cnt[2 * t] = p0;          // repurpose as cursors
    cnt[2 * t + 1] = p1;
    __syncthreads();

    for (int i = t; i < m; i += 256) {
        int2 pr = stage[e0 + i];
        int p = atomicAdd(&cnt[pr.y - nb0], 1);
        ssrc[p] = pr.x;
    }
}

// ---------------- x fp32 -> bf16, padded [M_PAD x 192] ----------------

__global__ __launch_bounds__(256) void k_cvt(const float* __restrict__ x,
                                             u16* __restrict__ xb) {
    int idx = blockIdx.x * 256 + threadIdx.x;
    int row = idx / 24;
    int c = idx - row * 24;
    int k0 = c * 8;
    float v[8];
#pragma unroll
    for (int j = 0; j < 8; ++j) {
        int k = k0 + j;
        v[j] = (row < N_NODES && k < IN_CH) ? x[(size_t)row * IN_CH + k] : 0.f;
    }
    int4 o;
    o.x = pk2(v[0], v[1]);
    o.y = pk2(v[2], v[3]);
    o.z = pk2(v[4], v[5]);
    o.w = pk2(v[6], v[7]);
    *(int4*)(xb + (size_t)row * 192 + k0) = o;
}

// ---------------- weight prep: Wl|Wr -> bf16 MFMA fragments ----------------

__global__ __launch_bounds__(64) void k_wprep(const float* __restrict__ Wl,
                                              const float* __restrict__ Wr,
                                              int Kact, u16* __restrict__ wf) {
    int lane = threadIdx.x;
    int kt = blockIdx.x >> 4;
    int ct = blockIdx.x & 15;
    int col = ct * 16 + (lane & 15);
    const float* W = (col < 128) ? Wl : Wr;
    int wcol = col & 127;
    float v[8];
#pragma unroll
    for (int j = 0; j < 8; ++j) {
        int row = kt * 32 + (lane >> 4) * 8 + j;
        v[j] = (row < Kact) ? W[(size_t)row * 128 + wcol] : 0.f;
    }
    int4 o;
    o.x = pk2(v[0], v[1]);
    o.y = pk2(v[2], v[3]);
    o.z = pk2(v[4], v[5]);
    o.w = pk2(v[6], v[7]);
    *(int4*)(wf + ((size_t)blockIdx.x * 64 + lane) * 8) = o;
}

// ---------------- MFMA projection: [64 x KP] @ [KP x 256] per block --------

template <int KP>
__global__ __launch_bounds__(256) void k_projmm(const u16* __restrict__ in,
                                                const u16* __restrict__ wf,
                                                const float* __restrict__ bias,
                                                u16* __restrict__ y,
                                                float* __restrict__ r) {
    constexpr int STR = KP + 8;
    constexpr int CH = KP / 8;
    __shared__ u16 sA[64 * STR];

    const int tid = threadIdx.x;
    const int n0 = blockIdx.x * 64;

    for (int c = tid; c < 64 * CH; c += 256) {
        int row = c / CH;
        int cc = c - row * CH;
        int4 v = *(const int4*)(in + (size_t)(n0 + row) * KP + cc * 8);
        *(int4*)(&sA[row * STR + cc * 8]) = v;
    }
    __syncthreads();

    const int wv = tid >> 6;
    const int lane = tid & 63;
    const int r16 = lane & 15;
    const int kq = lane >> 4;

    f32x4 acc[4][4];
#pragma unroll
    for (int a = 0; a < 4; ++a)
#pragma unroll
        for (int b = 0; b < 4; ++b) acc[a][b] = (f32x4){0.f, 0.f, 0.f, 0.f};

#pragma unroll
    for (int kt = 0; kt < KP / 32; ++kt) {
        short8 af[4], bf[4];
#pragma unroll
        for (int rt = 0; rt < 4; ++rt)
            af[rt] = *(const short8*)(&sA[(rt * 16 + r16) * STR + kt * 32 + kq * 8]);
#pragma unroll
        for (int c = 0; c < 4; ++c)
            bf[c] = *(const short8*)(wf + (((size_t)(kt * 16 + wv * 4 + c) * 64 + lane) * 8));
#pragma unroll
        for (int rt = 0; rt < 4; ++rt)
#pragma unroll
            for (int c = 0; c < 4; ++c)
                acc[rt][c] = __builtin_amdgcn_mfma_f32_16x16x32_bf16(af[rt], bf[c], acc[rt][c], 0, 0, 0);
    }

    if (wv < 2) {
#pragma unroll
        for (int rt = 0; rt < 4; ++rt)
#pragma unroll
            for (int c = 0; c < 4; ++c) {
                int col = wv * 64 + c * 16 + r16;
#pragma unroll
                for (int i = 0; i < 4; ++i) {
                    int row = n0 + rt * 16 + kq * 4 + i;
                    y[(size_t)row * 128 + col] = f2bf(acc[rt][c][i]);
                }
            }
    } else {
        float bv[4];
#pragma unroll
        for (int c = 0; c < 4; ++c) bv[c] = bias[(wv - 2) * 64 + c * 16 + r16];
#pragma unroll
        for (int rt = 0; rt < 4; ++rt)
#pragma unroll
            for (int c = 0; c < 4; ++c) {
                int col = (wv - 2) * 64 + c * 16 + r16;
#pragma unroll
                for (int i = 0; i < 4; ++i) {
                    int row = n0 + rt * 16 + kq * 4 + i;
                    r[(size_t)row * 128 + col] = acc[rt][c][i] + bv[c];
                }
            }
    }
}

// ---------------- aggregation: h = relu(mean_gather(yb) + r), bf16 out -----

__global__ __launch_bounds__(256) void k_aggb(const u16* __restrict__ yb,
                                              const float* __restrict__ r,
                                              const int* __restrict__ offsets,
                                              const int* __restrict__ ssrc,
                                              u16* __restrict__ h) {
    const int lane = threadIdx.x & 63;
    const int node = blockIdx.x * 4 + (threadIdx.x >> 6);
    const int g = lane >> 4;
    const int i = lane & 15;
    const int off0 = offsets[node];
    const int deg = offsets[node + 1] - off0;

    float acc[8] = {0.f, 0.f, 0.f, 0.f, 0.f, 0.f, 0.f, 0.f};

    for (int cb = 0; cb < deg; cb += 64) {
        int idxv = (cb + lane < deg) ? ssrc[off0 + cb + lane] : 0;
        int steps = min(16, (deg - cb + 3) >> 2);
        for (int s = 0; s < steps; ++s) {
            int e = cb + s * 4 + g;
            int srci = __shfl(idxv, s * 4 + g);
            if (e < deg) {
                int4 v = *(const int4*)(yb + (size_t)srci * 128 + i * 8);
                const unsigned* w = (const unsigned*)&v;
#pragma unroll
                for (int q = 0; q < 4; ++q) {
                    acc[q * 2]     += __uint_as_float(w[q] << 16);
                    acc[q * 2 + 1] += __uint_as_float(w[q] & 0xFFFF0000u);
                }
            }
        }
    }
#pragma unroll
    for (int q = 0; q < 8; ++q) {
        acc[q] += __shfl_xor(acc[q], 16);
        acc[q] += __shfl_xor(acc[q], 32);
    }
    if (g == 0) {
        float inv = 1.f / (float)max(deg, 1);
        const float4* rp = (const float4*)(r + (size_t)node * 128 + i * 8);
        float4 r0 = rp[0], r1 = rp[1];
        float o[8];
        o[0] = fmaxf(acc[0] * inv + r0.x, 0.f);
        o[1] = fmaxf(acc[1] * inv + r0.y, 0.f);
        o[2] = fmaxf(acc[2] * inv + r0.z, 0.f);
        o[3] = fmaxf(acc[3] * inv + r0.w, 0.f);
        o[4] = fmaxf(acc[4] * inv + r1.x, 0.f);
        o[5] = fmaxf(acc[5] * inv + r1.y, 0.f);
        o[6] = fmaxf(acc[6] * inv + r1.z, 0.f);
        o[7] = fmaxf(acc[7] * inv + r1.w, 0.f);
        int4 ov;
        ov.x = pk2(o[0], o[1]);
        ov.y = pk2(o[2], o[3]);
        ov.z = pk2(o[4], o[5]);
        ov.w = pk2(o[6], o[7]);
        *(int4*)(h + (size_t)node * 128 + i * 8) = ov;
    }
}

// ---------------- layer 2 projection (bf16 h -> 2ch) ----------------

__global__ __launch_bounds__(256) void k_proj2b(const u16* __restrict__ h,
                                                const float* __restrict__ Wl,
                                                const float* __restrict__ Wr,
                                                const float* __restrict__ bias,
                                                float* __restrict__ z,
                                                float* __restrict__ r2) {
    const int lane = threadIdx.x & 63;
    const int node = blockIdx.x * 4 + (threadIdx.x >> 6);
    unsigned hv = *(const unsigned*)(h + (size_t)node * 128 + lane * 2);
    float h0 = __uint_as_float(hv << 16);
    float h1 = __uint_as_float(hv & 0xFFFF0000u);
    float4 wl = *(const float4*)&Wl[lane * 4];
    float4 wr = *(const float4*)&Wr[lane * 4];
    float zl0 = h0 * wl.x + h1 * wl.z;
    float zl1 = h0 * wl.y + h1 * wl.w;
    float zr0 = h0 * wr.x + h1 * wr.z;
    float zr1 = h0 * wr.y + h1 * wr.w;
    for (int d = 32; d; d >>= 1) {
        zl0 += __shfl_xor(zl0, d);
        zl1 += __shfl_xor(zl1, d);
        zr0 += __shfl_xor(zr0, d);
        zr1 += __shfl_xor(zr1, d);
    }
    if (lane == 0) {
        z[node * 2 + 0] = zl0;
        z[node * 2 + 1] = zl1;
        r2[node * 2 + 0] = zr0 + bias[0];
        r2[node * 2 + 1] = zr1 + bias[1];
    }
}

// ---------------- layer 2 aggregation (2 channels) ----------------

__global__ __launch_bounds__(256) void k_agg2(const float* __restrict__ z,
                                              const float* __restrict__ r2,
                                              const int* __restrict__ offsets,
                                              const int* __restrict__ ssrc,
                                              float* __restrict__ out) {
    int n = blockIdx.x * 256 + threadIdx.x;
    if (n >= N_NODES) return;
    int off0 = offsets[n];
    int off1 = offsets[n + 1];
    float a0 = 0.f, a1 = 0.f;
    for (int e = off0; e < off1; ++e) {
        int s = ssrc[e];
        a0 += z[s * 2];
        a1 += z[s * 2 + 1];
    }
    float inv = 1.0f / (float)max(off1 - off0, 1);
    out[n * 2 + 0] = a0 * inv + r2[n * 2 + 0];
    out[n * 2 + 1] = a1 * inv + r2[n * 2 + 1];
}

// ---------------- launcher ----------------

extern "C" void kernel_launch(void* const* d_in, const int* in_sizes, int n_in,
                              void* d_out, int out_size, void* d_ws, size_t ws_size,
                              hipStream_t stream) {
    const float* x   = (const float*)d_in[0];
    const int*   ei  = (const int*)d_in[1];
    const float* Wl0 = (const float*)d_in[2];
    const float* bl0 = (const float*)d_in[3];
    const float* Wr0 = (const float*)d_in[4];
    const float* Wl1 = (const float*)d_in[5];
    const float* bl1 = (const float*)d_in[6];
    const float* Wr1 = (const float*)d_in[7];
    const float* Wl2 = (const float*)d_in[8];
    const float* bl2 = (const float*)d_in[9];
    const float* Wr2 = (const float*)d_in[10];
    float* out = (float*)d_out;

    const int* srcp = ei;
    const int* dstp = ei + N_EDGES;

    char* ws = (char*)d_ws;
    size_t off = 0;
    auto alloc = [&](size_t bytes) -> void* {
        void* p = ws + off;
        off += (bytes + 255) & ~(size_t)255;
        return p;
    };
    int* bcnt        = (int*)alloc(NBUCK * 4);
    int* bucket_base = (int*)alloc((NBUCK + 1) * 4);
    int* gcursor     = (int*)alloc(NBUCK * 4);
    int* offsets     = (int*)alloc((size_t)(N_NODES + 1) * 4);
    int2* stage      = (int2*)alloc((size_t)N_EDGES * 8);
    int* ssrc        = (int*)alloc((size_t)N_EDGES * 4);
    u16* xb          = (u16*)alloc((size_t)M_PAD * 192 * 2);   // reused as h0
    u16* wf0         = (u16*)alloc((size_t)192 * 256 * 2);
    u16* wf1         = (u16*)alloc((size_t)128 * 256 * 2);
    u16* ybuf        = (u16*)alloc((size_t)M_PAD * 128 * 2);   // reused as z/r2
    float* rbuf      = (float*)alloc((size_t)M_PAD * 128 * 4);
    u16* h1          = (u16*)alloc((size_t)M_PAD * 128 * 2);
    (void)ws_size; (void)n_in; (void)in_sizes; (void)out_size;

    u16* h0 = xb;
    float* z  = (float*)ybuf;
    float* r2 = (float*)((char*)ybuf + 1048576);

    // ---- graph build (two-level counting sort -> CSR by dst) ----
    hipMemsetAsync(bcnt, 0, NBUCK * 4, stream);
    const int NB_SC = (N_EDGES / 4 + 1023) / 1024;   // 245
    k_bincount<<<NB_SC, 256, 0, stream>>>(dstp, bcnt);
    k_bucketscan<<<1, 256, 0, stream>>>(bcnt, bucket_base, gcursor, offsets);
    k_scatter<<<NB_SC, 256, 0, stream>>>(srcp, dstp, gcursor, stage);
    k_csr<<<NBUCK, 256, 0, stream>>>(stage, bucket_base, offsets, ssrc);

    // ---- input/weight conversion ----
    k_cvt<<<(M_PAD * 24) / 256, 256, 0, stream>>>(x, xb);
    k_wprep<<<(192 / 32) * 16, 64, 0, stream>>>(Wl0, Wr0, IN_CH, wf0);
    k_wprep<<<(128 / 32) * 16, 64, 0, stream>>>(Wl1, Wr1, HID, wf1);

    // ---- layer 0 ----
    k_projmm<192><<<M_PAD / 64, 256, 0, stream>>>(xb, wf0, bl0, ybuf, rbuf);
    k_aggb<<<N_NODES / 4, 256, 0, stream>>>(ybuf, rbuf, offsets, ssrc, h0);

    // ---- layer 1 ----
    k_projmm<128><<<M_PAD / 64, 256, 0, stream>>>(h0, wf1, bl1, ybuf, rbuf);
    k_aggb<<<N_NODES / 4, 256, 0, stream>>>(ybuf, rbuf, offsets, ssrc, h1);

    // ---- layer 2 ----
    k_proj2b<<<N_NODES / 4, 256, 0, stream>>>(h1, Wl2, Wr2, bl2, z, r2);
    k_agg2<<<(N_NODES + 255) / 256, 256, 0, stream>>>(z, r2, offsets, ssrc, out);
}

// Round 4
// 237.605 us; speedup vs baseline: 2.3902x; 1.1094x over previous
//
#include <hip/hip_runtime.h>

#define N_NODES 100000
#define N_EDGES 1000000
#define IN_CH 166
#define HID 128
#define M_PAD 100032   // 1563 * 64
#define BSHIFT 9
#define NBUCK 196      // ceil(100000 / 512)

typedef unsigned short u16;
typedef __attribute__((ext_vector_type(8))) short short8;
typedef __attribute__((ext_vector_type(4))) float f32x4;

static __device__ __forceinline__ u16 f2bf(float f) {
    unsigned u = __float_as_uint(f);
    u += 0x7FFF + ((u >> 16) & 1);   // RNE
    return (u16)(u >> 16);
}
static __device__ __forceinline__ unsigned pk2(float a, float b) {
    return (unsigned)f2bf(a) | ((unsigned)f2bf(b) << 16);
}
static __device__ __forceinline__ float bf_lo(unsigned w) {
    return __uint_as_float(w << 16);
}
static __device__ __forceinline__ float bf_hi(unsigned w) {
    return __uint_as_float(w & 0xFFFF0000u);
}

// ================= graph build: two-level counting sort =================

__global__ __launch_bounds__(256) void k_bincount(const int* __restrict__ dst,
                                                  int* __restrict__ bcnt) {
    __shared__ int cnt[NBUCK];
    const int t = threadIdx.x;
    if (t < NBUCK) cnt[t] = 0;
    __syncthreads();
#pragma unroll
    for (int j = 0; j < 4; ++j) {
        int e4 = blockIdx.x * 1024 + j * 256 + t;
        if (e4 < N_EDGES / 4) {
            int4 d = ((const int4*)dst)[e4];
            atomicAdd(&cnt[d.x >> BSHIFT], 1);
            atomicAdd(&cnt[d.y >> BSHIFT], 1);
            atomicAdd(&cnt[d.z >> BSHIFT], 1);
            atomicAdd(&cnt[d.w >> BSHIFT], 1);
        }
    }
    __syncthreads();
    if (t < NBUCK && cnt[t] > 0) atomicAdd(&bcnt[t], cnt[t]);
}

__global__ __launch_bounds__(256) void k_bucketscan(const int* __restrict__ bcnt,
                                                    int* __restrict__ bucket_base,
                                                    int* __restrict__ gcursor,
                                                    int* __restrict__ offsets) {
    __shared__ int ws[256];
    const int t = threadIdx.x;
    int loc = (t < NBUCK) ? bcnt[t] : 0;
    ws[t] = loc;
    __syncthreads();
    int val = loc;
    for (int stp = 1; stp < 256; stp <<= 1) {
        int other = (t >= stp) ? ws[t - stp] : 0;
        __syncthreads();
        val += other;
        ws[t] = val;
        __syncthreads();
    }
    int excl = val - loc;
    if (t < NBUCK) {
        bucket_base[t] = excl;
        gcursor[t] = excl;
    }
    if (t == 255) bucket_base[NBUCK] = val;
    if (t == 0) offsets[N_NODES] = N_EDGES;
}

__global__ __launch_bounds__(256) void k_scatter(const int* __restrict__ src,
                                                 const int* __restrict__ dst,
                                                 int* __restrict__ gcursor,
                                                 int2* __restrict__ stage) {
    __shared__ int cnt[NBUCK];
    __shared__ int base[NBUCK];
    const int t = threadIdx.x;
    if (t < NBUCK) cnt[t] = 0;
    __syncthreads();

    int4 s4[4], d4[4];
    bool ok[4];
#pragma unroll
    for (int j = 0; j < 4; ++j) {
        int e4 = blockIdx.x * 1024 + j * 256 + t;
        ok[j] = (e4 < N_EDGES / 4);
        if (ok[j]) {
            s4[j] = ((const int4*)src)[e4];
            d4[j] = ((const int4*)dst)[e4];
            atomicAdd(&cnt[d4[j].x >> BSHIFT], 1);
            atomicAdd(&cnt[d4[j].y >> BSHIFT], 1);
            atomicAdd(&cnt[d4[j].z >> BSHIFT], 1);
            atomicAdd(&cnt[d4[j].w >> BSHIFT], 1);
        }
    }
    __syncthreads();
    if (t < NBUCK && cnt[t] > 0) base[t] = atomicAdd(&gcursor[t], cnt[t]);
    __syncthreads();

#pragma unroll
    for (int j = 0; j < 4; ++j) {
        if (ok[j]) {
            const int ss[4] = {s4[j].x, s4[j].y, s4[j].z, s4[j].w};
            const int dd[4] = {d4[j].x, d4[j].y, d4[j].z, d4[j].w};
#pragma unroll
            for (int q = 0; q < 4; ++q) {
                int b = dd[q] >> BSHIFT;
                int r = atomicSub(&cnt[b], 1) - 1;
                int2 pr;
                pr.x = ss[q];
                pr.y = dd[q];
                stage[base[b] + r] = pr;
            }
        }
    }
}

__global__ __launch_bounds__(256) void k_csr(const int2* __restrict__ stage,
                                             const int* __restrict__ bucket_base,
                                             int* __restrict__ offsets,
                                             int* __restrict__ ssrc) {
    __shared__ int cnt[512];
    __shared__ int ws[256];
    const int t = threadIdx.x;
    const int b = blockIdx.x;
    const int nb0 = b << BSHIFT;
    const int nn = min(512, N_NODES - nb0);
    const int e0 = bucket_base[b];
    const int m = bucket_base[b + 1] - e0;

    cnt[t] = 0;
    cnt[t + 256] = 0;
    __syncthreads();

    for (int i = t; i < m; i += 256) {
        int d = stage[e0 + i].y;
        atomicAdd(&cnt[d - nb0], 1);
    }
    __syncthreads();

    int c0 = cnt[2 * t];
    int c1 = cnt[2 * t + 1];
    int loc = c0 + c1;
    ws[t] = loc;
    __syncthreads();
    int val = loc;
    for (int stp = 1; stp < 256; stp <<= 1) {
        int other = (t >= stp) ? ws[t - stp] : 0;
        __syncthreads();
        val += other;
        ws[t] = val;
        __syncthreads();
    }
    int p0 = e0 + (val - loc);
    int p1 = p0 + c0;
    if (2 * t < nn) offsets[nb0 + 2 * t] = p0;
    if (2 * t + 1 < nn) offsets[nb0 + 2 * t + 1] = p1;
    cnt[2 * t] = p0;
    cnt[2 * t + 1] = p1;
    __syncthreads();

    for (int i = t; i < m; i += 256) {
        int2 pr = stage[e0 + i];
        int p = atomicAdd(&cnt[pr.y - nb0], 1);
        ssrc[p] = pr.x;
    }
}

// ---------------- weight prep: Wl|Wr -> bf16 MFMA fragments ----------------

__global__ __launch_bounds__(64) void k_wprep(const float* __restrict__ Wl,
                                              const float* __restrict__ Wr,
                                              int Kact, u16* __restrict__ wf) {
    int lane = threadIdx.x;
    int kt = blockIdx.x >> 4;
    int ct = blockIdx.x & 15;
    int col = ct * 16 + (lane & 15);
    const float* W = (col < 128) ? Wl : Wr;
    int wcol = col & 127;
    float v[8];
#pragma unroll
    for (int j = 0; j < 8; ++j) {
        int row = kt * 32 + (lane >> 4) * 8 + j;
        v[j] = (row < Kact) ? W[(size_t)row * 128 + wcol] : 0.f;
    }
    int4 o;
    o.x = pk2(v[0], v[1]);
    o.y = pk2(v[2], v[3]);
    o.z = pk2(v[4], v[5]);
    o.w = pk2(v[6], v[7]);
    *(int4*)(wf + ((size_t)blockIdx.x * 64 + lane) * 8) = o;
}

// ---------------- MFMA projection core (shared store epilogue) ----------

template <int KP>
static __device__ __forceinline__ void projmm_body(const u16* sA, int STR,
                                                   const u16* __restrict__ wf,
                                                   const float* __restrict__ bias,
                                                   u16* __restrict__ y,
                                                   u16* __restrict__ rb, int n0) {
    const int tid = threadIdx.x;
    const int wv = tid >> 6;
    const int lane = tid & 63;
    const int r16 = lane & 15;
    const int kq = lane >> 4;

    f32x4 acc[4][4];
#pragma unroll
    for (int a = 0; a < 4; ++a)
#pragma unroll
        for (int b = 0; b < 4; ++b) acc[a][b] = (f32x4){0.f, 0.f, 0.f, 0.f};

#pragma unroll
    for (int kt = 0; kt < KP / 32; ++kt) {
        short8 af[4], bf[4];
#pragma unroll
        for (int rt = 0; rt < 4; ++rt)
            af[rt] = *(const short8*)(&sA[(rt * 16 + r16) * STR + kt * 32 + kq * 8]);
#pragma unroll
        for (int c = 0; c < 4; ++c)
            bf[c] = *(const short8*)(wf + (((size_t)(kt * 16 + wv * 4 + c) * 64 + lane) * 8));
#pragma unroll
        for (int rt = 0; rt < 4; ++rt)
#pragma unroll
            for (int c = 0; c < 4; ++c)
                acc[rt][c] = __builtin_amdgcn_mfma_f32_16x16x32_bf16(af[rt], bf[c], acc[rt][c], 0, 0, 0);
    }

    if (wv < 2) {
#pragma unroll
        for (int rt = 0; rt < 4; ++rt)
#pragma unroll
            for (int c = 0; c < 4; ++c) {
                int col = wv * 64 + c * 16 + r16;
#pragma unroll
                for (int i = 0; i < 4; ++i) {
                    int row = n0 + rt * 16 + kq * 4 + i;
                    y[(size_t)row * 128 + col] = f2bf(acc[rt][c][i]);
                }
            }
    } else {
        float bv[4];
#pragma unroll
        for (int c = 0; c < 4; ++c) bv[c] = bias[(wv - 2) * 64 + c * 16 + r16];
#pragma unroll
        for (int rt = 0; rt < 4; ++rt)
#pragma unroll
            for (int c = 0; c < 4; ++c) {
                int col = (wv - 2) * 64 + c * 16 + r16;
#pragma unroll
                for (int i = 0; i < 4; ++i) {
                    int row = n0 + rt * 16 + kq * 4 + i;
                    rb[(size_t)row * 128 + col] = f2bf(acc[rt][c][i] + bv[c]);
                }
            }
    }
}

// layer 0: fp32 x [N,166] read directly, packed to bf16 in LDS, K padded to 192
__global__ __launch_bounds__(256) void k_projmm0(const float* __restrict__ in,
                                                 const u16* __restrict__ wf,
                                                 const float* __restrict__ bias,
                                                 u16* __restrict__ y,
                                                 u16* __restrict__ rb) {
    constexpr int KP = 192;
    constexpr int STR = KP + 8;
    __shared__ u16 sA[64 * STR];
    const int tid = threadIdx.x;
    const int n0 = blockIdx.x * 64;

    // 96 u32-columns per row: 83 loaded from x (float2 -> bf16x2), rest zero
    for (int c = tid; c < 64 * 96; c += 256) {
        int row = c / 96;
        int cc = c - row * 96;
        unsigned val = 0;
        int gr = n0 + row;
        if (cc < 83 && gr < N_NODES) {
            float2 v = ((const float2*)in)[(size_t)gr * 83 + cc];
            val = pk2(v.x, v.y);
        }
        *(unsigned*)(&sA[row * STR + cc * 2]) = val;
    }
    __syncthreads();
    projmm_body<KP>(sA, STR, wf, bias, y, rb, n0);
}

// layer 1: bf16 input [M_PAD,128]
__global__ __launch_bounds__(256) void k_projmm1(const u16* __restrict__ in,
                                                 const u16* __restrict__ wf,
                                                 const float* __restrict__ bias,
                                                 u16* __restrict__ y,
                                                 u16* __restrict__ rb) {
    constexpr int KP = 128;
    constexpr int STR = KP + 8;
    __shared__ u16 sA[64 * STR];
    const int tid = threadIdx.x;
    const int n0 = blockIdx.x * 64;

    for (int c = tid; c < 64 * 16; c += 256) {
        int row = c >> 4;
        int cc = c & 15;
        int4 v = *(const int4*)(in + (size_t)(n0 + row) * KP + cc * 8);
        *(int4*)(&sA[row * STR + cc * 8]) = v;
    }
    __syncthreads();
    projmm_body<KP>(sA, STR, wf, bias, y, rb, n0);
}

// ---------------- aggregation: h = relu(mean_gather(yb) + rb), bf16 -------
// one 16-lane group per node: 4 nodes/wave, 16 nodes/block. No shfl, no
// cross-lane reduce; srci load is uniform within the group (broadcast).

__global__ __launch_bounds__(256) void k_aggb(const u16* __restrict__ yb,
                                              const u16* __restrict__ rb,
                                              const int* __restrict__ offsets,
                                              const int* __restrict__ ssrc,
                                              u16* __restrict__ h) {
    const int lane = threadIdx.x & 63;
    const int wv = threadIdx.x >> 6;
    const int g = lane >> 4;     // node subgroup within wave
    const int i = lane & 15;     // channel chunk (8 ch)
    const int node = blockIdx.x * 16 + wv * 4 + g;
    const int off0 = offsets[node];
    const int deg = offsets[node + 1] - off0;

    float acc[8] = {0.f, 0.f, 0.f, 0.f, 0.f, 0.f, 0.f, 0.f};

    int e = 0;
    for (; e + 1 < deg; e += 2) {
        int s0 = ssrc[off0 + e];
        int s1 = ssrc[off0 + e + 1];
        int4 v0 = *(const int4*)(yb + (size_t)s0 * 128 + i * 8);
        int4 v1 = *(const int4*)(yb + (size_t)s1 * 128 + i * 8);
        const unsigned* w0 = (const unsigned*)&v0;
        const unsigned* w1 = (const unsigned*)&v1;
#pragma unroll
        for (int q = 0; q < 4; ++q) {
            acc[q * 2]     += bf_lo(w0[q]) + bf_lo(w1[q]);
            acc[q * 2 + 1] += bf_hi(w0[q]) + bf_hi(w1[q]);
        }
    }
    if (e < deg) {
        int s0 = ssrc[off0 + e];
        int4 v0 = *(const int4*)(yb + (size_t)s0 * 128 + i * 8);
        const unsigned* w0 = (const unsigned*)&v0;
#pragma unroll
        for (int q = 0; q < 4; ++q) {
            acc[q * 2]     += bf_lo(w0[q]);
            acc[q * 2 + 1] += bf_hi(w0[q]);
        }
    }

    float inv = 1.f / (float)max(deg, 1);
    int4 rv = *(const int4*)(rb + (size_t)node * 128 + i * 8);
    const unsigned* rw = (const unsigned*)&rv;
    float o[8];
#pragma unroll
    for (int q = 0; q < 4; ++q) {
        o[q * 2]     = fmaxf(acc[q * 2] * inv + bf_lo(rw[q]), 0.f);
        o[q * 2 + 1] = fmaxf(acc[q * 2 + 1] * inv + bf_hi(rw[q]), 0.f);
    }
    int4 ov;
    ov.x = pk2(o[0], o[1]);
    ov.y = pk2(o[2], o[3]);
    ov.z = pk2(o[4], o[5]);
    ov.w = pk2(o[6], o[7]);
    *(int4*)(h + (size_t)node * 128 + i * 8) = ov;
}

// ---------------- layer 2 projection (bf16 h -> 2ch) ----------------

__global__ __launch_bounds__(256) void k_proj2b(const u16* __restrict__ h,
                                                const float* __restrict__ Wl,
                                                const float* __restrict__ Wr,
                                                const float* __restrict__ bias,
                                                float* __restrict__ z,
                                                float* __restrict__ r2) {
    const int lane = threadIdx.x & 63;
    const int node = blockIdx.x * 4 + (threadIdx.x >> 6);
    unsigned hv = *(const unsigned*)(h + (size_t)node * 128 + lane * 2);
    float h0 = bf_lo(hv);
    float h1 = bf_hi(hv);
    float4 wl = *(const float4*)&Wl[lane * 4];
    float4 wr = *(const float4*)&Wr[lane * 4];
    float zl0 = h0 * wl.x + h1 * wl.z;
    float zl1 = h0 * wl.y + h1 * wl.w;
    float zr0 = h0 * wr.x + h1 * wr.z;
    float zr1 = h0 * wr.y + h1 * wr.w;
    for (int d = 32; d; d >>= 1) {
        zl0 += __shfl_xor(zl0, d);
        zl1 += __shfl_xor(zl1, d);
        zr0 += __shfl_xor(zr0, d);
        zr1 += __shfl_xor(zr1, d);
    }
    if (lane == 0) {
        z[node * 2 + 0] = zl0;
        z[node * 2 + 1] = zl1;
        r2[node * 2 + 0] = zr0 + bias[0];
        r2[node * 2 + 1] = zr1 + bias[1];
    }
}

// ---------------- layer 2 aggregation (2 channels) ----------------

__global__ __launch_bounds__(256) void k_agg2(const float* __restrict__ z,
                                              const float* __restrict__ r2,
                                              const int* __restrict__ offsets,
                                              const int* __restrict__ ssrc,
                                              float* __restrict__ out) {
    int n = blockIdx.x * 256 + threadIdx.x;
    if (n >= N_NODES) return;
    int off0 = offsets[n];
    int off1 = offsets[n + 1];
    float a0 = 0.f, a1 = 0.f;
    for (int e = off0; e < off1; ++e) {
        int s = ssrc[e];
        a0 += z[s * 2];
        a1 += z[s * 2 + 1];
    }
    float inv = 1.0f / (float)max(off1 - off0, 1);
    out[n * 2 + 0] = a0 * inv + r2[n * 2 + 0];
    out[n * 2 + 1] = a1 * inv + r2[n * 2 + 1];
}

// ---------------- launcher ----------------

extern "C" void kernel_launch(void* const* d_in, const int* in_sizes, int n_in,
                              void* d_out, int out_size, void* d_ws, size_t ws_size,
                              hipStream_t stream) {
    const float* x   = (const float*)d_in[0];
    const int*   ei  = (const int*)d_in[1];
    const float* Wl0 = (const float*)d_in[2];
    const float* bl0 = (const float*)d_in[3];
    const float* Wr0 = (const float*)d_in[4];
    const float* Wl1 = (const float*)d_in[5];
    const float* bl1 = (const float*)d_in[6];
    const float* Wr1 = (const float*)d_in[7];
    const float* Wl2 = (const float*)d_in[8];
    const float* bl2 = (const float*)d_in[9];
    const float* Wr2 = (const float*)d_in[10];
    float* out = (float*)d_out;

    const int* srcp = ei;
    const int* dstp = ei + N_EDGES;

    char* ws = (char*)d_ws;
    size_t off = 0;
    auto alloc = [&](size_t bytes) -> void* {
        void* p = ws + off;
        off += (bytes + 255) & ~(size_t)255;
        return p;
    };
    int* bcnt        = (int*)alloc(NBUCK * 4);
    int* bucket_base = (int*)alloc((NBUCK + 1) * 4);
    int* gcursor     = (int*)alloc(NBUCK * 4);
    int* offsets     = (int*)alloc((size_t)(N_NODES + 1) * 4);
    int2* stage      = (int2*)alloc((size_t)N_EDGES * 8);
    int* ssrc        = (int*)alloc((size_t)N_EDGES * 4);
    u16* wf0         = (u16*)alloc((size_t)192 * 256 * 2);
    u16* wf1         = (u16*)alloc((size_t)128 * 256 * 2);
    u16* ybuf        = (u16*)alloc((size_t)M_PAD * 128 * 2);
    u16* rbuf        = (u16*)alloc((size_t)M_PAD * 128 * 2);
    u16* h0          = (u16*)alloc((size_t)M_PAD * 128 * 2);
    u16* h1          = (u16*)alloc((size_t)M_PAD * 128 * 2);
    (void)ws_size; (void)n_in; (void)in_sizes; (void)out_size;

    float* z  = (float*)ybuf;                      // dead after layer-1 aggb
    float* r2 = (float*)((char*)ybuf + 1048576);

    // ---- graph build (two-level counting sort -> CSR by dst) ----
    hipMemsetAsync(bcnt, 0, NBUCK * 4, stream);
    const int NB_SC = (N_EDGES / 4 + 1023) / 1024;   // 245
    k_bincount<<<NB_SC, 256, 0, stream>>>(dstp, bcnt);
    k_bucketscan<<<1, 256, 0, stream>>>(bcnt, bucket_base, gcursor, offsets);
    k_scatter<<<NB_SC, 256, 0, stream>>>(srcp, dstp, gcursor, stage);
    k_csr<<<NBUCK, 256, 0, stream>>>(stage, bucket_base, offsets, ssrc);

    // ---- weight conversion ----
    k_wprep<<<(192 / 32) * 16, 64, 0, stream>>>(Wl0, Wr0, IN_CH, wf0);
    k_wprep<<<(128 / 32) * 16, 64, 0, stream>>>(Wl1, Wr1, HID, wf1);

    // ---- layer 0 (reads fp32 x directly) ----
    k_projmm0<<<M_PAD / 64, 256, 0, stream>>>(x, wf0, bl0, ybuf, rbuf);
    k_aggb<<<N_NODES / 16, 256, 0, stream>>>(ybuf, rbuf, offsets, ssrc, h0);

    // ---- layer 1 ----
    k_projmm1<<<M_PAD / 64, 256, 0, stream>>>(h0, wf1, bl1, ybuf, rbuf);
    k_aggb<<<N_NODES / 16, 256, 0, stream>>>(ybuf, rbuf, offsets, ssrc, h1);

    // ---- layer 2 ----
    k_proj2b<<<N_NODES / 4, 256, 0, stream>>>(h1, Wl2, Wr2, bl2, z, r2);
    k_agg2<<<(N_NODES + 255) / 256, 256, 0, stream>>>(z, r2, offsets, ssrc, out);
}

// Round 5
// 226.830 us; speedup vs baseline: 2.5037x; 1.0475x over previous
//
#include <hip/hip_runtime.h>

#define N_NODES 100000
#define N_EDGES 1000000
#define IN_CH 166
#define HID 128
#define M_PAD 100032   // 1563 * 64
#define BSHIFT 9
#define NBUCK 196      // ceil(100000 / 512)

typedef unsigned short u16;
typedef __attribute__((ext_vector_type(8))) short short8;
typedef __attribute__((ext_vector_type(4))) float f32x4;

static __device__ __forceinline__ u16 f2bf(float f) {
    unsigned u = __float_as_uint(f);
    u += 0x7FFF + ((u >> 16) & 1);   // RNE
    return (u16)(u >> 16);
}
static __device__ __forceinline__ unsigned pk2(float a, float b) {
    return (unsigned)f2bf(a) | ((unsigned)f2bf(b) << 16);
}
static __device__ __forceinline__ float bf_lo(unsigned w) {
    return __uint_as_float(w << 16);
}
static __device__ __forceinline__ float bf_hi(unsigned w) {
    return __uint_as_float(w & 0xFFFF0000u);
}

// ================= graph build: two-level counting sort =================

__global__ __launch_bounds__(256) void k_bincount(const int* __restrict__ dst,
                                                  int* __restrict__ bcnt) {
    __shared__ int cnt[NBUCK];
    const int t = threadIdx.x;
    if (t < NBUCK) cnt[t] = 0;
    __syncthreads();
#pragma unroll
    for (int j = 0; j < 4; ++j) {
        int e4 = blockIdx.x * 1024 + j * 256 + t;
        if (e4 < N_EDGES / 4) {
            int4 d = ((const int4*)dst)[e4];
            atomicAdd(&cnt[d.x >> BSHIFT], 1);
            atomicAdd(&cnt[d.y >> BSHIFT], 1);
            atomicAdd(&cnt[d.z >> BSHIFT], 1);
            atomicAdd(&cnt[d.w >> BSHIFT], 1);
        }
    }
    __syncthreads();
    if (t < NBUCK && cnt[t] > 0) atomicAdd(&bcnt[t], cnt[t]);
}

__global__ __launch_bounds__(256) void k_bucketscan(const int* __restrict__ bcnt,
                                                    int* __restrict__ bucket_base,
                                                    int* __restrict__ gcursor,
                                                    int* __restrict__ offsets) {
    __shared__ int ws[256];
    const int t = threadIdx.x;
    int loc = (t < NBUCK) ? bcnt[t] : 0;
    ws[t] = loc;
    __syncthreads();
    int val = loc;
    for (int stp = 1; stp < 256; stp <<= 1) {
        int other = (t >= stp) ? ws[t - stp] : 0;
        __syncthreads();
        val += other;
        ws[t] = val;
        __syncthreads();
    }
    int excl = val - loc;
    if (t < NBUCK) {
        bucket_base[t] = excl;
        gcursor[t] = excl;
    }
    if (t == 255) bucket_base[NBUCK] = val;
    if (t == 0) offsets[N_NODES] = N_EDGES;
}

__global__ __launch_bounds__(256) void k_scatter(const int* __restrict__ src,
                                                 const int* __restrict__ dst,
                                                 int* __restrict__ gcursor,
                                                 int2* __restrict__ stage) {
    __shared__ int cnt[NBUCK];
    __shared__ int base[NBUCK];
    const int t = threadIdx.x;
    if (t < NBUCK) cnt[t] = 0;
    __syncthreads();

    int4 s4[4], d4[4];
    bool ok[4];
#pragma unroll
    for (int j = 0; j < 4; ++j) {
        int e4 = blockIdx.x * 1024 + j * 256 + t;
        ok[j] = (e4 < N_EDGES / 4);
        if (ok[j]) {
            s4[j] = ((const int4*)src)[e4];
            d4[j] = ((const int4*)dst)[e4];
            atomicAdd(&cnt[d4[j].x >> BSHIFT], 1);
            atomicAdd(&cnt[d4[j].y >> BSHIFT], 1);
            atomicAdd(&cnt[d4[j].z >> BSHIFT], 1);
            atomicAdd(&cnt[d4[j].w >> BSHIFT], 1);
        }
    }
    __syncthreads();
    if (t < NBUCK && cnt[t] > 0) base[t] = atomicAdd(&gcursor[t], cnt[t]);
    __syncthreads();

#pragma unroll
    for (int j = 0; j < 4; ++j) {
        if (ok[j]) {
            const int ss[4] = {s4[j].x, s4[j].y, s4[j].z, s4[j].w};
            const int dd[4] = {d4[j].x, d4[j].y, d4[j].z, d4[j].w};
#pragma unroll
            for (int q = 0; q < 4; ++q) {
                int b = dd[q] >> BSHIFT;
                int r = atomicSub(&cnt[b], 1) - 1;
                int2 pr;
                pr.x = ss[q];
                pr.y = dd[q];
                stage[base[b] + r] = pr;
            }
        }
    }
}

__global__ __launch_bounds__(256) void k_csr(const int2* __restrict__ stage,
                                             const int* __restrict__ bucket_base,
                                             int* __restrict__ offsets,
                                             int* __restrict__ ssrc) {
    __shared__ int cnt[512];
    __shared__ int ws[256];
    const int t = threadIdx.x;
    const int b = blockIdx.x;
    const int nb0 = b << BSHIFT;
    const int nn = min(512, N_NODES - nb0);
    const int e0 = bucket_base[b];
    const int m = bucket_base[b + 1] - e0;

    cnt[t] = 0;
    cnt[t + 256] = 0;
    __syncthreads();

    for (int i = t; i < m; i += 256) {
        int d = stage[e0 + i].y;
        atomicAdd(&cnt[d - nb0], 1);
    }
    __syncthreads();

    int c0 = cnt[2 * t];
    int c1 = cnt[2 * t + 1];
    int loc = c0 + c1;
    ws[t] = loc;
    __syncthreads();
    int val = loc;
    for (int stp = 1; stp < 256; stp <<= 1) {
        int other = (t >= stp) ? ws[t - stp] : 0;
        __syncthreads();
        val += other;
        ws[t] = val;
        __syncthreads();
    }
    int p0 = e0 + (val - loc);
    int p1 = p0 + c0;
    if (2 * t < nn) offsets[nb0 + 2 * t] = p0;
    if (2 * t + 1 < nn) offsets[nb0 + 2 * t + 1] = p1;
    cnt[2 * t] = p0;
    cnt[2 * t + 1] = p1;
    __syncthreads();

    for (int i = t; i < m; i += 256) {
        int2 pr = stage[e0 + i];
        int p = atomicAdd(&cnt[pr.y - nb0], 1);
        ssrc[p] = pr.x;
    }
}

// ---------------- weight prep: Wl|Wr -> bf16 MFMA fragments ----------------

__global__ __launch_bounds__(64) void k_wprep(const float* __restrict__ Wl,
                                              const float* __restrict__ Wr,
                                              int Kact, u16* __restrict__ wf) {
    int lane = threadIdx.x;
    int kt = blockIdx.x >> 4;
    int ct = blockIdx.x & 15;
    int col = ct * 16 + (lane & 15);
    const float* W = (col < 128) ? Wl : Wr;
    int wcol = col & 127;
    float v[8];
#pragma unroll
    for (int j = 0; j < 8; ++j) {
        int row = kt * 32 + (lane >> 4) * 8 + j;
        v[j] = (row < Kact) ? W[(size_t)row * 128 + wcol] : 0.f;
    }
    int4 o;
    o.x = pk2(v[0], v[1]);
    o.y = pk2(v[2], v[3]);
    o.z = pk2(v[4], v[5]);
    o.w = pk2(v[6], v[7]);
    *(int4*)(wf + ((size_t)blockIdx.x * 64 + lane) * 8) = o;
}

// ---------------- MFMA projection core: 8 waves, 32x64 per wave ----------
// block tile 64 rows x 256 cols; wave (rg = wv&1, cg = wv>>1):
// rows rg*32..+31, cols cg*64..+63. acc[2][4] = 32 AGPR -> high occupancy.

template <int KP>
static __device__ __forceinline__ void projmm_body(const u16* sA,
                                                   const u16* __restrict__ wf,
                                                   const float* __restrict__ bias,
                                                   u16* __restrict__ y,
                                                   u16* __restrict__ rb, int n0) {
    constexpr int STR = KP + 8;
    const int tid = threadIdx.x;
    const int wv = tid >> 6;
    const int lane = tid & 63;
    const int rg = wv & 1;       // row group (32 rows)
    const int cg = wv >> 1;      // col group (64 cols)
    const int r16 = lane & 15;
    const int kq = lane >> 4;

    f32x4 acc[2][4];
#pragma unroll
    for (int a = 0; a < 2; ++a)
#pragma unroll
        for (int b = 0; b < 4; ++b) acc[a][b] = (f32x4){0.f, 0.f, 0.f, 0.f};

#pragma unroll
    for (int kt = 0; kt < KP / 32; ++kt) {
        short8 af[2], bf[4];
#pragma unroll
        for (int rt = 0; rt < 2; ++rt)
            af[rt] = *(const short8*)(&sA[(rg * 32 + rt * 16 + r16) * STR + kt * 32 + kq * 8]);
#pragma unroll
        for (int c = 0; c < 4; ++c)
            bf[c] = *(const short8*)(wf + (((size_t)(kt * 16 + cg * 4 + c) * 64 + lane) * 8));
#pragma unroll
        for (int rt = 0; rt < 2; ++rt)
#pragma unroll
            for (int c = 0; c < 4; ++c)
                acc[rt][c] = __builtin_amdgcn_mfma_f32_16x16x32_bf16(af[rt], bf[c], acc[rt][c], 0, 0, 0);
    }

    if (cg < 2) {
#pragma unroll
        for (int rt = 0; rt < 2; ++rt)
#pragma unroll
            for (int c = 0; c < 4; ++c) {
                int col = cg * 64 + c * 16 + r16;
#pragma unroll
                for (int i = 0; i < 4; ++i) {
                    int row = n0 + rg * 32 + rt * 16 + kq * 4 + i;
                    y[(size_t)row * 128 + col] = f2bf(acc[rt][c][i]);
                }
            }
    } else {
        float bv[4];
#pragma unroll
        for (int c = 0; c < 4; ++c) bv[c] = bias[(cg - 2) * 64 + c * 16 + r16];
#pragma unroll
        for (int rt = 0; rt < 2; ++rt)
#pragma unroll
            for (int c = 0; c < 4; ++c) {
                int col = (cg - 2) * 64 + c * 16 + r16;
#pragma unroll
                for (int i = 0; i < 4; ++i) {
                    int row = n0 + rg * 32 + rt * 16 + kq * 4 + i;
                    rb[(size_t)row * 128 + col] = f2bf(acc[rt][c][i] + bv[c]);
                }
            }
    }
}

// layer 0: fp32 x [N,166] read directly, packed to bf16 in LDS, K padded to 192
__global__ __launch_bounds__(512, 4) void k_projmm0(const float* __restrict__ in,
                                                    const u16* __restrict__ wf,
                                                    const float* __restrict__ bias,
                                                    u16* __restrict__ y,
                                                    u16* __restrict__ rb) {
    constexpr int KP = 192;
    constexpr int STR = KP + 8;
    __shared__ u16 sA[64 * STR];
    const int tid = threadIdx.x;
    const int n0 = blockIdx.x * 64;

    // 96 u32-columns per row: 83 loaded from x (float2 -> bf16x2), rest zero
#pragma unroll
    for (int it = 0; it < 12; ++it) {
        int c = it * 512 + tid;
        int row = c / 96;
        int cc = c - row * 96;
        unsigned val = 0;
        int gr = n0 + row;
        if (cc < 83 && gr < N_NODES) {
            float2 v = ((const float2*)in)[(size_t)gr * 83 + cc];
            val = pk2(v.x, v.y);
        }
        *(unsigned*)(&sA[row * STR + cc * 2]) = val;
    }
    __syncthreads();
    projmm_body<KP>(sA, wf, bias, y, rb, n0);
}

// layer 1: bf16 input [M_PAD,128]
__global__ __launch_bounds__(512, 4) void k_projmm1(const u16* __restrict__ in,
                                                    const u16* __restrict__ wf,
                                                    const float* __restrict__ bias,
                                                    u16* __restrict__ y,
                                                    u16* __restrict__ rb) {
    constexpr int KP = 128;
    constexpr int STR = KP + 8;
    __shared__ u16 sA[64 * STR];
    const int tid = threadIdx.x;
    const int n0 = blockIdx.x * 64;

#pragma unroll
    for (int it = 0; it < 2; ++it) {
        int c = it * 512 + tid;
        int row = c >> 4;
        int cc = c & 15;
        int4 v = *(const int4*)(in + (size_t)(n0 + row) * KP + cc * 8);
        *(int4*)(&sA[row * STR + cc * 8]) = v;
    }
    __syncthreads();
    projmm_body<KP>(sA, wf, bias, y, rb, n0);
}

// ---------------- aggregation: h = relu(mean_gather(yb) + rb), bf16 -------
// one 16-lane group per node: 4 nodes/wave, 16 nodes/block.

__global__ __launch_bounds__(256) void k_aggb(const u16* __restrict__ yb,
                                              const u16* __restrict__ rb,
                                              const int* __restrict__ offsets,
                                              const int* __restrict__ ssrc,
                                              u16* __restrict__ h) {
    const int lane = threadIdx.x & 63;
    const int wv = threadIdx.x >> 6;
    const int g = lane >> 4;
    const int i = lane & 15;
    const int node = blockIdx.x * 16 + wv * 4 + g;
    const int off0 = offsets[node];
    const int deg = offsets[node + 1] - off0;

    float acc[8] = {0.f, 0.f, 0.f, 0.f, 0.f, 0.f, 0.f, 0.f};

    int e = 0;
    for (; e + 1 < deg; e += 2) {
        int s0 = ssrc[off0 + e];
        int s1 = ssrc[off0 + e + 1];
        int4 v0 = *(const int4*)(yb + (size_t)s0 * 128 + i * 8);
        int4 v1 = *(const int4*)(yb + (size_t)s1 * 128 + i * 8);
        const unsigned* w0 = (const unsigned*)&v0;
        const unsigned* w1 = (const unsigned*)&v1;
#pragma unroll
        for (int q = 0; q < 4; ++q) {
            acc[q * 2]     += bf_lo(w0[q]) + bf_lo(w1[q]);
            acc[q * 2 + 1] += bf_hi(w0[q]) + bf_hi(w1[q]);
        }
    }
    if (e < deg) {
        int s0 = ssrc[off0 + e];
        int4 v0 = *(const int4*)(yb + (size_t)s0 * 128 + i * 8);
        const unsigned* w0 = (const unsigned*)&v0;
#pragma unroll
        for (int q = 0; q < 4; ++q) {
            acc[q * 2]     += bf_lo(w0[q]);
            acc[q * 2 + 1] += bf_hi(w0[q]);
        }
    }

    float inv = 1.f / (float)max(deg, 1);
    int4 rv = *(const int4*)(rb + (size_t)node * 128 + i * 8);
    const unsigned* rw = (const unsigned*)&rv;
    float o[8];
#pragma unroll
    for (int q = 0; q < 4; ++q) {
        o[q * 2]     = fmaxf(acc[q * 2] * inv + bf_lo(rw[q]), 0.f);
        o[q * 2 + 1] = fmaxf(acc[q * 2 + 1] * inv + bf_hi(rw[q]), 0.f);
    }
    int4 ov;
    ov.x = pk2(o[0], o[1]);
    ov.y = pk2(o[2], o[3]);
    ov.z = pk2(o[4], o[5]);
    ov.w = pk2(o[6], o[7]);
    *(int4*)(h + (size_t)node * 128 + i * 8) = ov;
}

// ---------------- layer 2 projection (bf16 h -> 2ch) ----------------

__global__ __launch_bounds__(256) void k_proj2b(const u16* __restrict__ h,
                                                const float* __restrict__ Wl,
                                                const float* __restrict__ Wr,
                                                const float* __restrict__ bias,
                                                float* __restrict__ z,
                                                float* __restrict__ r2) {
    const int lane = threadIdx.x & 63;
    const int node = blockIdx.x * 4 + (threadIdx.x >> 6);
    unsigned hv = *(const unsigned*)(h + (size_t)node * 128 + lane * 2);
    float h0 = bf_lo(hv);
    float h1 = bf_hi(hv);
    float4 wl = *(const float4*)&Wl[lane * 4];
    float4 wr = *(const float4*)&Wr[lane * 4];
    float zl0 = h0 * wl.x + h1 * wl.z;
    float zl1 = h0 * wl.y + h1 * wl.w;
    float zr0 = h0 * wr.x + h1 * wr.z;
    float zr1 = h0 * wr.y + h1 * wr.w;
    for (int d = 32; d; d >>= 1) {
        zl0 += __shfl_xor(zl0, d);
        zl1 += __shfl_xor(zl1, d);
        zr0 += __shfl_xor(zr0, d);
        zr1 += __shfl_xor(zr1, d);
    }
    if (lane == 0) {
        z[node * 2 + 0] = zl0;
        z[node * 2 + 1] = zl1;
        r2[node * 2 + 0] = zr0 + bias[0];
        r2[node * 2 + 1] = zr1 + bias[1];
    }
}

// ---------------- layer 2 aggregation (2 channels) ----------------

__global__ __launch_bounds__(256) void k_agg2(const float* __restrict__ z,
                                              const float* __restrict__ r2,
                                              const int* __restrict__ offsets,
                                              const int* __restrict__ ssrc,
                                              float* __restrict__ out) {
    int n = blockIdx.x * 256 + threadIdx.x;
    if (n >= N_NODES) return;
    int off0 = offsets[n];
    int off1 = offsets[n + 1];
    float a0 = 0.f, a1 = 0.f;
    for (int e = off0; e < off1; ++e) {
        int s = ssrc[e];
        a0 += z[s * 2];
        a1 += z[s * 2 + 1];
    }
    float inv = 1.0f / (float)max(off1 - off0, 1);
    out[n * 2 + 0] = a0 * inv + r2[n * 2 + 0];
    out[n * 2 + 1] = a1 * inv + r2[n * 2 + 1];
}

// ---------------- launcher ----------------

extern "C" void kernel_launch(void* const* d_in, const int* in_sizes, int n_in,
                              void* d_out, int out_size, void* d_ws, size_t ws_size,
                              hipStream_t stream) {
    const float* x   = (const float*)d_in[0];
    const int*   ei  = (const int*)d_in[1];
    const float* Wl0 = (const float*)d_in[2];
    const float* bl0 = (const float*)d_in[3];
    const float* Wr0 = (const float*)d_in[4];
    const float* Wl1 = (const float*)d_in[5];
    const float* bl1 = (const float*)d_in[6];
    const float* Wr1 = (const float*)d_in[7];
    const float* Wl2 = (const float*)d_in[8];
    const float* bl2 = (const float*)d_in[9];
    const float* Wr2 = (const float*)d_in[10];
    float* out = (float*)d_out;

    const int* srcp = ei;
    const int* dstp = ei + N_EDGES;

    char* ws = (char*)d_ws;
    size_t off = 0;
    auto alloc = [&](size_t bytes) -> void* {
        void* p = ws + off;
        off += (bytes + 255) & ~(size_t)255;
        return p;
    };
    int* bcnt        = (int*)alloc(NBUCK * 4);
    int* bucket_base = (int*)alloc((NBUCK + 1) * 4);
    int* gcursor     = (int*)alloc(NBUCK * 4);
    int* offsets     = (int*)alloc((size_t)(N_NODES + 1) * 4);
    int2* stage      = (int2*)alloc((size_t)N_EDGES * 8);
    int* ssrc        = (int*)alloc((size_t)N_EDGES * 4);
    u16* wf0         = (u16*)alloc((size_t)192 * 256 * 2);
    u16* wf1         = (u16*)alloc((size_t)128 * 256 * 2);
    u16* ybuf        = (u16*)alloc((size_t)M_PAD * 128 * 2);
    u16* rbuf        = (u16*)alloc((size_t)M_PAD * 128 * 2);
    u16* h0          = (u16*)alloc((size_t)M_PAD * 128 * 2);
    u16* h1          = (u16*)alloc((size_t)M_PAD * 128 * 2);
    (void)ws_size; (void)n_in; (void)in_sizes; (void)out_size;

    float* z  = (float*)ybuf;                      // dead after layer-1 aggb
    float* r2 = (float*)((char*)ybuf + 1048576);

    // ---- graph build (two-level counting sort -> CSR by dst) ----
    hipMemsetAsync(bcnt, 0, NBUCK * 4, stream);
    const int NB_SC = (N_EDGES / 4 + 1023) / 1024;   // 245
    k_bincount<<<NB_SC, 256, 0, stream>>>(dstp, bcnt);
    k_bucketscan<<<1, 256, 0, stream>>>(bcnt, bucket_base, gcursor, offsets);
    k_scatter<<<NB_SC, 256, 0, stream>>>(srcp, dstp, gcursor, stage);
    k_csr<<<NBUCK, 256, 0, stream>>>(stage, bucket_base, offsets, ssrc);

    // ---- weight conversion ----
    k_wprep<<<(192 / 32) * 16, 64, 0, stream>>>(Wl0, Wr0, IN_CH, wf0);
    k_wprep<<<(128 / 32) * 16, 64, 0, stream>>>(Wl1, Wr1, HID, wf1);

    // ---- layer 0 (reads fp32 x directly) ----
    k_projmm0<<<M_PAD / 64, 512, 0, stream>>>(x, wf0, bl0, ybuf, rbuf);
    k_aggb<<<N_NODES / 16, 256, 0, stream>>>(ybuf, rbuf, offsets, ssrc, h0);

    // ---- layer 1 ----
    k_projmm1<<<M_PAD / 64, 512, 0, stream>>>(h0, wf1, bl1, ybuf, rbuf);
    k_aggb<<<N_NODES / 16, 256, 0, stream>>>(ybuf, rbuf, offsets, ssrc, h1);

    // ---- layer 2 ----
    k_proj2b<<<N_NODES / 4, 256, 0, stream>>>(h1, Wl2, Wr2, bl2, z, r2);
    k_agg2<<<(N_NODES + 255) / 256, 256, 0, stream>>>(z, r2, offsets, ssrc, out);
}